// Round 7
// baseline (246.843 us; speedup 1.0000x reference)
//
#include <hip/hip_runtime.h>
#include <hip/hip_bf16.h>

// out[e] = tanh(prop[idx_i[e]] @ wi1) @ wi2 + tanh(prop[idx_j[e]] @ wj1) @ wj2
// Factored: F_I = mlp(prop, wi*), F_J = mlp(prop, wj*)  [per-node, 16x fewer FLOPs]
//           out[e] = F_I[idx_i[e]] + F_J[idx_j[e]]      [gather-add]
//
// R4: bf16 F tables -> 202 us.  R5: L3 column-phasing REGRESSED (223) ->
//     memory-side L3 can't be made to retain tables under the write stream.
// R6: XCD-SHARDED tables targeting demand-side L2 instead. Tables stored as
//     F[slab][node][16cols] (8 slabs of 16 cols); gather blocks pick
//     slab = blockIdx.x & 7, which the dispatcher round-robins onto XCDs, so
//     each XCD's read working set is 2 x 50000 x 32 B = 3.2 MB < 4 MB L2,
//     line-perfect (contiguous slab). Reads then come from XCD-local L2
//     (34.5 TB/s aggregate); HBM sees only the 410 MB output stream + 51 MB
//     idx re-reads + 26 MB compulsory table fills.

typedef __attribute__((ext_vector_type(8))) short bf16x8;   // 8 bf16 (4 VGPRs)
typedef __attribute__((ext_vector_type(4))) float f32x4;    // MFMA accumulator / 16B vec

__device__ __forceinline__ unsigned short f2bf(float f) {
    // round-to-nearest-even fp32 -> bf16 (inputs are normal floats)
    unsigned int u = __float_as_uint(f);
    unsigned int r = (u + 0x7fffu + ((u >> 16) & 1u)) >> 16;
    return (unsigned short)r;
}
__device__ __forceinline__ float bf2f(short b) {
    return __uint_as_float((unsigned int)(unsigned short)b << 16);
}

#define LDK 136  // padded LDS row stride in bf16 elems: 272 B (16B-aligned reads)

// Core: tanh(src[map(row)] @ W1) @ W2, 64 rows/block, 4 waves x 16 rows.
// BF16OUT: write bf16 tables in XCD-sharded layout dstb[slab][row][16]
//          (slab == nb, slab stride = sstride elems). Else fp32 [row][128].
template <bool BF16OUT>
__device__ __forceinline__ void mlp_block(
    const float* __restrict__ src, const int* __restrict__ idx,
    const float* __restrict__ W1, const float* __restrict__ W2,
    float* __restrict__ dstf, unsigned short* __restrict__ dstb, size_t sstride,
    int n_rows, int accumulate, int bid)
{
    __shared__ short Wt[128][LDK];      // W^T as bf16 bits: Wt[n][k] = W[k][n]
    __shared__ short Tl[4][16][LDK];    // per-wave tanh(h) tile (A-operand for GEMM2)

    const int tid  = threadIdx.x;
    const int lane = tid & 63;
    const int wave = tid >> 6;
    const int lo   = lane & 15;   // col within 16-tile / A row
    const int q    = lane >> 4;   // k-group (A/B) / row-group (C/D)
    const int r0   = bid * 64;

    // ---- stage W1^T into LDS (coalesced global read, ds_write_b64) ----
    {
        const int n  = tid & 127;
        const int kq = (tid >> 7) * 4;
        for (int k0 = kq; k0 < 128; k0 += 8) {
            ushort4 p;
            p.x = f2bf(W1[(k0 + 0) * 128 + n]);
            p.y = f2bf(W1[(k0 + 1) * 128 + n]);
            p.z = f2bf(W1[(k0 + 2) * 128 + n]);
            p.w = f2bf(W1[(k0 + 3) * 128 + n]);
            *reinterpret_cast<ushort4*>(&Wt[n][k0]) = p;
        }
    }
    __syncthreads();

    // ---- A fragments: 16 rows per wave, row = lane&15, k = (lane>>4)*8 + i ----
    int arow   = r0 + wave * 16 + lo;
    int arow_c = arow < n_rows ? arow : n_rows - 1;
    int srow   = idx ? idx[arow_c] : arow_c;
    const float4* ap = reinterpret_cast<const float4*>(src + (size_t)srow * 128);

    bf16x8 afr[4];
    #pragma unroll
    for (int kk = 0; kk < 4; ++kk) {
        float4 p0 = ap[kk * 8 + q * 2 + 0];
        float4 p1 = ap[kk * 8 + q * 2 + 1];
        afr[kk][0] = (short)f2bf(p0.x); afr[kk][1] = (short)f2bf(p0.y);
        afr[kk][2] = (short)f2bf(p0.z); afr[kk][3] = (short)f2bf(p0.w);
        afr[kk][4] = (short)f2bf(p1.x); afr[kk][5] = (short)f2bf(p1.y);
        afr[kk][6] = (short)f2bf(p1.z); afr[kk][7] = (short)f2bf(p1.w);
    }

    // ---- GEMM1: h = A @ W1 ----
    f32x4 acc[8];
    #pragma unroll
    for (int nb = 0; nb < 8; ++nb) acc[nb] = f32x4{0.f, 0.f, 0.f, 0.f};
    #pragma unroll
    for (int nb = 0; nb < 8; ++nb) {
        const int col = nb * 16 + lo;
        #pragma unroll
        for (int kk = 0; kk < 4; ++kk) {
            bf16x8 b = *reinterpret_cast<const bf16x8*>(&Wt[col][kk * 32 + q * 8]);
            acc[nb] = __builtin_amdgcn_mfma_f32_16x16x32_bf16(afr[kk], b, acc[nb], 0, 0, 0);
        }
    }

    __syncthreads();  // all waves done reading W1^T before overwrite

    // ---- stage W2^T (reuse Wt) ----
    {
        const int n  = tid & 127;
        const int kq = (tid >> 7) * 4;
        for (int k0 = kq; k0 < 128; k0 += 8) {
            ushort4 p;
            p.x = f2bf(W2[(k0 + 0) * 128 + n]);
            p.y = f2bf(W2[(k0 + 1) * 128 + n]);
            p.z = f2bf(W2[(k0 + 2) * 128 + n]);
            p.w = f2bf(W2[(k0 + 3) * 128 + n]);
            *reinterpret_cast<ushort4*>(&Wt[n][k0]) = p;
        }
    }
    // ---- tanh, C/D layout (col=lane&15, row=(lane>>4)*4+r) -> Tl row-major ----
    #pragma unroll
    for (int nb = 0; nb < 8; ++nb) {
        #pragma unroll
        for (int r = 0; r < 4; ++r) {
            Tl[wave][q * 4 + r][nb * 16 + lo] = (short)f2bf(tanhf(acc[nb][r]));
        }
    }
    __syncthreads();

    // ---- A2 fragments from tanh tile (row = lane&15, k-contiguous) ----
    bf16x8 a2[4];
    #pragma unroll
    for (int kk = 0; kk < 4; ++kk)
        a2[kk] = *reinterpret_cast<const bf16x8*>(&Tl[wave][lo][kk * 32 + q * 8]);

    // ---- GEMM2: y = tanh(h) @ W2 ----
    f32x4 acc2[8];
    #pragma unroll
    for (int nb = 0; nb < 8; ++nb) acc2[nb] = f32x4{0.f, 0.f, 0.f, 0.f};
    #pragma unroll
    for (int nb = 0; nb < 8; ++nb) {
        const int col = nb * 16 + lo;
        #pragma unroll
        for (int kk = 0; kk < 4; ++kk) {
            bf16x8 b = *reinterpret_cast<const bf16x8*>(&Wt[col][kk * 32 + q * 8]);
            acc2[nb] = __builtin_amdgcn_mfma_f32_16x16x32_bf16(a2[kk], b, acc2[nb], 0, 0, 0);
        }
    }

    // ---- store; C/D layout: col = nb*16+lo, row = r0+wave*16+q*4+r ----
    #pragma unroll
    for (int r = 0; r < 4; ++r) {
        int row = r0 + wave * 16 + q * 4 + r;
        if (row < n_rows) {
            #pragma unroll
            for (int nb = 0; nb < 8; ++nb) {
                if (BF16OUT) {
                    // sharded: slab = nb, col-in-slab = lo
                    dstb[(size_t)nb * sstride + (size_t)row * 16 + lo] = f2bf(acc2[nb][r]);
                } else {
                    int c = nb * 16 + lo;
                    float* drow = dstf + (size_t)row * 128;
                    if (accumulate) drow[c] += acc2[nb][r];
                    else            drow[c]  = acc2[nb][r];
                }
            }
        }
    }
}

// Merged per-node MLPs -> sharded bf16 tables: blocks [0,nblk) -> FI; rest -> FJ.
__global__ __launch_bounds__(256) void mlp2_kernel(
    const float* __restrict__ src,
    const float* __restrict__ w11, const float* __restrict__ w12,
    const float* __restrict__ w21, const float* __restrict__ w22,
    unsigned short* __restrict__ FI, unsigned short* __restrict__ FJ,
    int n_rows, int nblk)
{
    const bool second = (int)blockIdx.x >= nblk;
    mlp_block<true>(src, nullptr,
                    second ? w21 : w11, second ? w22 : w12,
                    nullptr, second ? FJ : FI, (size_t)n_rows * 16, n_rows, 0,
                    second ? (int)blockIdx.x - nblk : (int)blockIdx.x);
}

// Fallback per-edge MLP (workspace too small), fp32 accumulate into out.
__global__ __launch_bounds__(256) void mlp_kernel(
    const float* __restrict__ src, const int* __restrict__ idx,
    const float* __restrict__ W1, const float* __restrict__ W2,
    float* __restrict__ dst, int n_rows, int accumulate)
{
    mlp_block<false>(src, idx, W1, W2, dst, nullptr, 0, n_rows, accumulate,
                     (int)blockIdx.x);
}

// XCD-sharded gather-add: out[e, slab*16+c] = FI_s[slab][ni][c] + FJ_s[slab][nj][c].
// slab = blockIdx.x & 7 -> dispatch round-robin pins each slab to one XCD;
// per-XCD read set = 3.2 MB (L2-resident, line-perfect). 2 lanes/edge: each
// lane reads 16 B from each slab row and NT-stores 32 B (64 B/edge contiguous).
__global__ __launch_bounds__(256) void gather_add_kernel(
    const unsigned short* __restrict__ FI, const unsigned short* __restrict__ FJ,
    const int* __restrict__ idx_i, const int* __restrict__ idx_j,
    float* __restrict__ out, int n_edges, int n_nodes, int epc)
{
    const int slab  = blockIdx.x & 7;    // XCD id heuristic (round-robin dispatch)
    const int chunk = blockIdx.x >> 3;
    const size_t soff = (size_t)slab * n_nodes * 16;
    const unsigned short* fi = FI + soff;
    const unsigned short* fj = FJ + soff;
    const int h  = threadIdx.x & 1;      // 8-col half within the 16-col slab
    const int t2 = threadIdx.x >> 1;

    int e_beg = chunk * epc;
    int e_end = e_beg + epc; if (e_end > n_edges) e_end = n_edges;

    for (int e = e_beg + t2; e < e_end; e += 128) {
        const int ni = idx_i[e];
        const int nj = idx_j[e];
        bf16x8 a = *reinterpret_cast<const bf16x8*>(&fi[(size_t)ni * 16 + h * 8]);
        bf16x8 b = *reinterpret_cast<const bf16x8*>(&fj[(size_t)nj * 16 + h * 8]);
        f32x4 vlo, vhi;
        #pragma unroll
        for (int k = 0; k < 4; ++k) {
            vlo[k] = bf2f(a[k])     + bf2f(b[k]);
            vhi[k] = bf2f(a[k + 4]) + bf2f(b[k + 4]);
        }
        f32x4* op = reinterpret_cast<f32x4*>(&out[(size_t)e * 128 + slab * 16 + h * 8]);
        __builtin_nontemporal_store(vlo, op);      // write-once stream, no L2 alloc
        __builtin_nontemporal_store(vhi, op + 1);
    }
}

extern "C" void kernel_launch(void* const* d_in, const int* in_sizes, int n_in,
                              void* d_out, int out_size, void* d_ws, size_t ws_size,
                              hipStream_t stream)
{
    const float* prop  = (const float*)d_in[0];
    const int*   idx_i = (const int*)d_in[1];
    const int*   idx_j = (const int*)d_in[2];
    const float* wi1   = (const float*)d_in[3];
    const float* wi2   = (const float*)d_in[4];
    const float* wj1   = (const float*)d_in[5];
    const float* wj2   = (const float*)d_in[6];
    float* out = (float*)d_out;

    const int n_nodes = in_sizes[0] / 128;
    const int n_edges = in_sizes[1];

    const size_t f_elems = (size_t)n_nodes * 128;
    const size_t need    = 2 * f_elems * sizeof(unsigned short);

    if (ws_size >= need) {
        // Fast path: per-node MLPs into sharded bf16 tables, then XCD-sharded gather.
        unsigned short* FI = (unsigned short*)d_ws;
        unsigned short* FJ = FI + f_elems;
        int nblk = (n_nodes + 63) / 64;
        mlp2_kernel<<<2 * nblk, 256, 0, stream>>>(prop, wi1, wi2, wj1, wj2,
                                                  FI, FJ, n_nodes, nblk);

        // 2048 blocks = 256 chunks x 8 slabs; slab k's 256 blocks land on XCD k
        // (8 blocks/CU x 32 CU, fully co-resident).
        int epc = (n_edges + 255) / 256;
        gather_add_kernel<<<2048, 256, 0, stream>>>(FI, FJ, idx_i, idx_j,
                                                    out, n_edges, n_nodes, epc);
    } else {
        // Fallback (workspace too small): per-edge MLP with gather, then accumulate pass.
        int nblk = (n_edges + 63) / 64;
        mlp_kernel<<<nblk, 256, 0, stream>>>(prop, idx_i, wi1, wi2, out, n_edges, 0);
        mlp_kernel<<<nblk, 256, 0, stream>>>(prop, idx_j, wj1, wj2, out, n_edges, 1);
    }
}